// Round 9
// baseline (502.435 us; speedup 1.0000x reference)
//
#include <hip/hip_runtime.h>
#include <hip/hip_bf16.h>

#define N_NODES 16000
#define N_EDGES 256000

// ---- workspace layout (4-byte units) — total 816001 * 4B = 3.26 MB (validated size) ----
#define OFF_SD     0          // int2  256000  (src,dst) per CSR slot, sorted by dst
#define OFF_SIMB   512000     // float 256000  raw sim -> normalized a (in place)
#define OFF_CNT    768000     // int   16000   per-dst degree
#define OFF_START  784000     // int   16001   CSR row offsets
#define OFF_CUR    800001     // int   16000   fill cursors

__device__ __forceinline__ float dot16(const float* h, const float* w) {
  float r = 0.f;
#pragma unroll
  for (int t = 0; t < 16; ++t) r = fmaf(h[t], w[t], r);
  return r;
}

__device__ __forceinline__ void load16(const float* w, float* r) {
#pragma unroll
  for (int t = 0; t < 16; ++t) r[t] = w[t];   // 4x ds_read_b128, reused for 2 edges
}

// load a 40-float row (rows are 160B = 16B-aligned) via 10 x float4
__device__ __forceinline__ void load_row40(const float* __restrict__ p, float* xr) {
  const float4* rp = reinterpret_cast<const float4*>(p);
#pragma unroll
  for (int q = 0; q < 10; ++q) {
    float4 f = rp[q];
    xr[4 * q + 0] = f.x; xr[4 * q + 1] = f.y; xr[4 * q + 2] = f.z; xr[4 * q + 3] = f.w;
  }
}

struct EdgeGeom { float vhx, vhy, vhz, y1x, y1y, y1z; };

// geometry + radial basis + h = silu(rad @ W1n); W1 (LDS) [b*16+t], pre-scaled by 1/sqrt(32)
__device__ __forceinline__ void edge_h(const float* __restrict__ pos, int s, int d,
                                       const float* W1, float* h, EdgeGeom& g) {
  float vx = pos[3 * d + 0] - pos[3 * s + 0];
  float vy = pos[3 * d + 1] - pos[3 * s + 1];
  float vz = pos[3 * d + 2] - pos[3 * s + 2];
  float dist = sqrtf(fmaf(vx, vx, fmaf(vy, vy, vz * vz)));
  float dsafe = fmaxf(dist, 1e-6f);
  float rinv = 1.0f / dsafe;
  g.vhx = vx * rinv; g.vhy = vy * rinv; g.vhz = vz * rinv;
  g.y1x = 1.7320508075688772f * g.vhx;
  g.y1y = 1.7320508075688772f * g.vhy;
  g.y1z = 1.7320508075688772f * g.vhz;
  float pre[16];
#pragma unroll
  for (int t = 0; t < 16; ++t) pre[t] = 0.f;
  float sx, cx;
  sincosf(1.2566370614359172f * dsafe, &sx, &cx);   // pi/R_CUT * dsafe
  cx = fminf(1.f, fmaxf(-1.f, cx));
  float twoc = 2.f * cx;
  float sprev = 0.f, scur = sx;
  float rscale = (dist < 2.5f) ? (5.059644256269407f * rinv) : 0.f;  // sqrt(2/2.5)*sqrt(32)
#pragma unroll
  for (int b = 0; b < 32; ++b) {
    float radb = rscale * scur;
#pragma unroll
    for (int t = 0; t < 16; ++t) pre[t] = fmaf(radb, W1[16 * b + t], pre[t]);
    float snext = fmaf(twoc, scur, -sprev);
    sprev = scur; scur = snext;
  }
#pragma unroll
  for (int t = 0; t < 16; ++t) h[t] = pre[t] / (1.f + __expf(-pre[t]));  // silu
}

// ================= CSR build =================
__global__ void k_hist(const int* __restrict__ edst, int* __restrict__ cnt) {
  int e = blockIdx.x * 256 + threadIdx.x;
  atomicAdd(&cnt[edst[e]], 1);
}

__global__ void __launch_bounds__(1024) k_scan(const int* __restrict__ cnt,
                                               int* __restrict__ start, int* __restrict__ cur) {
  __shared__ int part[1024];
  int t = threadIdx.x;
  int base = t * 16;
  int local[16];
  int sum = 0;
#pragma unroll
  for (int i = 0; i < 16; ++i) {
    int idx = base + i;
    int c = (idx < N_NODES) ? cnt[idx] : 0;
    local[i] = sum; sum += c;
  }
  part[t] = sum;
  __syncthreads();
  for (int off = 1; off < 1024; off <<= 1) {
    int v = (t >= off) ? part[t - off] : 0;
    __syncthreads();
    part[t] += v;
    __syncthreads();
  }
  int prev = (t == 0) ? 0 : part[t - 1];
#pragma unroll
  for (int i = 0; i < 16; ++i) {
    int idx = base + i;
    if (idx < N_NODES) { int st = prev + local[i]; start[idx] = st; cur[idx] = st; }
  }
  if (t == 0) start[N_NODES] = N_EDGES;
}

__global__ void k_fill(const int* __restrict__ esrc, const int* __restrict__ edst,
                       int* __restrict__ cur, int2* __restrict__ sd) {
  int e = blockIdx.x * 256 + threadIdx.x;
  int d = edst[e];
  int slot = atomicAdd(&cur[d], 1);
  sd[slot] = make_int2(esrc[e], d);   // single 8B scattered store
}

// ================= pass 1 (slot-parallel): q + k TP + raw sim =================
// LDS (floats): [0,512) W1K/sqrt32 | [512,5120) W2K^T [col*16+t]*(1/sqrt16/sqrt24)
//               [5120,5248) WQS*0.25 | [5248,5280) WQV/sqrt8
//               [5280,5344) WSS/sqrt80 | [5344,5360) WVV/(sqrt80*sqrt3)
__global__ void __launch_bounds__(256) k_edge1(
    const float* __restrict__ pos, const float* __restrict__ x,
    const float* __restrict__ Wq_s, const float* __restrict__ Wq_v,
    const float* __restrict__ Wk1, const float* __restrict__ Wk2,
    const float* __restrict__ Wss, const float* __restrict__ Wvv,
    const int2* __restrict__ sd, float* __restrict__ simb) {
  __shared__ float L[5360];
  for (int i = threadIdx.x; i < 5360; i += 256) {
    float v;
    if (i < 512) v = Wk1[i] * 0.17677669529663687f;
    else if (i < 5120) {
      int j = i - 512; int col = j >> 4, t = j & 15;
      v = Wk2[t * 288 + col] * 0.051031036307982884f;
    }
    else if (i < 5248) v = Wq_s[i - 5120] * 0.25f;
    else if (i < 5280) v = Wq_v[i - 5248] * 0.3535533905932738f;
    else if (i < 5344) v = Wss[i - 5280] * 0.11180339887498948f;
    else               v = Wvv[i - 5344] * 0.06454972243679028f;
    L[i] = v;
  }
  __syncthreads();

  int j = blockIdx.x * 256 + threadIdx.x;
  int2 e = sd[j];
  int s = e.x, d = e.y;
  float h[16]; EdgeGeom g;
  edge_h(pos, s, d, L, h, g);

  float qd[8], qvd[12];
  {
    float xd[40];
    load_row40(x + 40 * d, xd);   // consecutive slots share d -> L1-resident
#pragma unroll
    for (int o = 0; o < 8; ++o) qd[o] = 0.f;
#pragma unroll
    for (int i = 0; i < 16; ++i)
#pragma unroll
      for (int o = 0; o < 8; ++o) qd[o] = fmaf(xd[i], L[5120 + 8 * i + o], qd[o]);
#pragma unroll
    for (int k = 0; k < 12; ++k) qvd[k] = 0.f;
#pragma unroll
    for (int i = 0; i < 8; ++i)
#pragma unroll
      for (int o = 0; o < 4; ++o)
#pragma unroll
        for (int c = 0; c < 3; ++c)
          qvd[3 * o + c] = fmaf(xd[16 + 3 * i + c], L[5248 + 4 * i + o], qvd[3 * o + c]);
  }

  float xr[40];
  load_row40(x + 40 * s, xr);
  const float* xs = xr;
  const float* xv = xr + 16;
  float B[8];
#pragma unroll
  for (int i = 0; i < 8; ++i)
    B[i] = fmaf(xv[3 * i], g.vhx, fmaf(xv[3 * i + 1], g.vhy, xv[3 * i + 2] * g.vhz));

  const float* W2 = L + 512;
  float ks[8];
#pragma unroll
  for (int o = 0; o < 8; ++o) {
    float acc = 0.f;
#pragma unroll
    for (int i = 0; i < 16; ++i) acc = fmaf(xs[i], dot16(h, W2 + ((i * 8 + o) << 4)), acc);
#pragma unroll
    for (int i = 0; i < 8; ++i)  acc = fmaf(B[i], dot16(h, W2 + ((128 + i * 8 + o) << 4)), acc);
    ks[o] = acc;
  }
  float kv[12];
#pragma unroll
  for (int o = 0; o < 4; ++o) {
    float s1 = 0.f;
#pragma unroll
    for (int i = 0; i < 16; ++i) s1 = fmaf(xs[i], dot16(h, W2 + ((192 + i * 4 + o) << 4)), s1);
    float s2x = 0.f, s2y = 0.f, s2z = 0.f;
#pragma unroll
    for (int i = 0; i < 8; ++i) {
      float w = dot16(h, W2 + ((256 + i * 4 + o) << 4));
      s2x = fmaf(xv[3 * i], w, s2x);
      s2y = fmaf(xv[3 * i + 1], w, s2y);
      s2z = fmaf(xv[3 * i + 2], w, s2z);
    }
    kv[3 * o]     = fmaf(g.y1x, s1, s2x);
    kv[3 * o + 1] = fmaf(g.y1y, s1, s2y);
    kv[3 * o + 2] = fmaf(g.y1z, s1, s2z);
  }

  float sim = 0.f;
#pragma unroll
  for (int jj = 0; jj < 8; ++jj) {
    float t = 0.f;
#pragma unroll
    for (int i = 0; i < 8; ++i) t = fmaf(qd[i], L[5280 + 8 * i + jj], t);
    sim = fmaf(t, ks[jj], sim);
  }
#pragma unroll
  for (int jj = 0; jj < 4; ++jj)
#pragma unroll
    for (int c = 0; c < 3; ++c) {
      float t = 0.f;
#pragma unroll
      for (int i = 0; i < 4; ++i) t = fmaf(qvd[3 * i + c], L[5344 + 4 * i + jj], t);
      sim = fmaf(t, kv[3 * jj + c], sim);
    }
  simb[j] = sim;
}

// ================= exact per-dst softmax: simb <- exp(sim - max)/Z =================
__global__ void k_norm(const int* __restrict__ start, float* __restrict__ simb) {
  int n = blockIdx.x * 256 + threadIdx.x;
  if (n >= N_NODES) return;
  int a = start[n], b = start[n + 1];
  if (a == b) return;
  float m = -3.4e38f;
  for (int j = a; j < b; ++j) m = fmaxf(m, simb[j]);
  float Z = 0.f;
  for (int j = a; j < b; ++j) { float t = __expf(simb[j] - m); simb[j] = t; Z += t; }
  float inv = 1.f / Z;
  for (int j = a; j < b; ++j) simb[j] *= inv;
}

__device__ __forceinline__ float segred(float v, const bool* same) {
#pragma unroll
  for (int k = 0; k < 6; ++k) {
    float ov = __shfl_down(v, 1 << k, 64);
    v += same[k] ? ov : 0.f;
  }
  return v;
}

// ================= pass 2: v TP, 2 edges/lane (W2 fragments reused), segmented scatter ========
// LDS: [0,512) W1V/sqrt32 | [512,9728) W2V^T [col*16+t]*(1/sqrt16/sqrt24)
// Each wave covers 128 consecutive slots: window A = base+lane, window B = base+64+lane.
__global__ void __launch_bounds__(256) k_edge2(
    const float* __restrict__ pos, const float* __restrict__ x,
    const float* __restrict__ Wv1, const float* __restrict__ Wv2,
    const int2* __restrict__ sd, const float* __restrict__ ab, float* __restrict__ out) {
  __shared__ float L[9728];
  for (int i = threadIdx.x; i < 9728; i += 256) {
    float v;
    if (i < 512) v = Wv1[i] * 0.17677669529663687f;
    else {
      int j = i - 512; int col = j >> 4, t = j & 15;
      v = Wv2[t * 576 + col] * 0.051031036307982884f;
    }
    L[i] = v;
  }
  __syncthreads();

  int wave = threadIdx.x >> 6, lane = threadIdx.x & 63;
  int base = blockIdx.x * 512 + wave * 128;   // 500 blocks * 512 slots = 256000 exact
  int jA = base + lane, jB = base + 64 + lane;
  int2 eA = sd[jA], eB = sd[jB];
  int dA = eA.y, dB = eB.y;

  bool sameA[6], sameB[6];
#pragma unroll
  for (int k = 0; k < 6; ++k) {
    int da = __shfl_down(dA, 1 << k, 64);
    int db = __shfl_down(dB, 1 << k, 64);
    bool in = (lane + (1 << k)) < 64;
    sameA[k] = in && (da == dA);
    sameB[k] = in && (db == dB);
  }
  int dpA = __shfl_up(dA, 1, 64), dpB = __shfl_up(dB, 1, 64);
  bool headA = (lane == 0) || (dpA != dA);
  bool headB = (lane == 0) || (dpB != dB);

  float hA[16], hB[16]; EdgeGeom gA, gB;
  edge_h(pos, eA.x, dA, L, hA, gA);
  edge_h(pos, eB.x, dB, L, hB, gB);
  float xrA[40], xrB[40];
  load_row40(x + 40 * eA.x, xrA);
  load_row40(x + 40 * eB.x, xrB);
  const float* xsA = xrA; const float* xvA = xrA + 16;
  const float* xsB = xrB; const float* xvB = xrB + 16;
  float BA[8], BB[8];
#pragma unroll
  for (int i = 0; i < 8; ++i) {
    BA[i] = fmaf(xvA[3 * i], gA.vhx, fmaf(xvA[3 * i + 1], gA.vhy, xvA[3 * i + 2] * gA.vhz));
    BB[i] = fmaf(xvB[3 * i], gB.vhx, fmaf(xvB[3 * i + 1], gB.vhy, xvB[3 * i + 2] * gB.vhz));
  }
  float aA = ab[jA], aB = ab[jB];
  const float* W2 = L + 512;
  float* opA = out + 40 * dA;
  float* opB = out + 40 * dB;

#pragma unroll
  for (int o = 0; o < 16; ++o) {
    float accA = 0.f, accB = 0.f;
    float w[16];
#pragma unroll
    for (int i = 0; i < 16; ++i) {
      load16(W2 + ((i * 16 + o) << 4), w);
      accA = fmaf(xsA[i], dot16(hA, w), accA);
      accB = fmaf(xsB[i], dot16(hB, w), accB);
    }
#pragma unroll
    for (int i = 0; i < 8; ++i) {
      load16(W2 + ((256 + i * 16 + o) << 4), w);
      accA = fmaf(BA[i], dot16(hA, w), accA);
      accB = fmaf(BB[i], dot16(hB, w), accB);
    }
    float vA = segred(aA * accA, sameA);
    if (headA) atomicAdd(opA + o, vA);
    float vB = segred(aB * accB, sameB);
    if (headB) atomicAdd(opB + o, vB);
  }
#pragma unroll
  for (int o = 0; o < 8; ++o) {
    float s1A = 0.f, s1B = 0.f;
    float w[16];
#pragma unroll
    for (int i = 0; i < 16; ++i) {
      load16(W2 + ((384 + i * 8 + o) << 4), w);
      s1A = fmaf(xsA[i], dot16(hA, w), s1A);
      s1B = fmaf(xsB[i], dot16(hB, w), s1B);
    }
    float s2Ax = 0.f, s2Ay = 0.f, s2Az = 0.f, s2Bx = 0.f, s2By = 0.f, s2Bz = 0.f;
#pragma unroll
    for (int i = 0; i < 8; ++i) {
      load16(W2 + ((512 + i * 8 + o) << 4), w);
      float wwA = dot16(hA, w), wwB = dot16(hB, w);
      s2Ax = fmaf(xvA[3 * i], wwA, s2Ax);
      s2Ay = fmaf(xvA[3 * i + 1], wwA, s2Ay);
      s2Az = fmaf(xvA[3 * i + 2], wwA, s2Az);
      s2Bx = fmaf(xvB[3 * i], wwB, s2Bx);
      s2By = fmaf(xvB[3 * i + 1], wwB, s2By);
      s2Bz = fmaf(xvB[3 * i + 2], wwB, s2Bz);
    }
    float vcA[3], vcB[3];
    vcA[0] = aA * fmaf(gA.y1x, s1A, s2Ax);
    vcA[1] = aA * fmaf(gA.y1y, s1A, s2Ay);
    vcA[2] = aA * fmaf(gA.y1z, s1A, s2Az);
    vcB[0] = aB * fmaf(gB.y1x, s1B, s2Bx);
    vcB[1] = aB * fmaf(gB.y1y, s1B, s2By);
    vcB[2] = aB * fmaf(gB.y1z, s1B, s2Bz);
#pragma unroll
    for (int c = 0; c < 3; ++c) {
      float vA = segred(vcA[c], sameA);
      if (headA) atomicAdd(opA + 16 + 3 * o + c, vA);
      float vB = segred(vcB[c], sameB);
      if (headB) atomicAdd(opB + 16 + 3 * o + c, vB);
    }
  }
}

extern "C" void kernel_launch(void* const* d_in, const int* in_sizes, int n_in,
                              void* d_out, int out_size, void* d_ws, size_t ws_size,
                              hipStream_t stream) {
  (void)in_sizes; (void)n_in; (void)out_size; (void)ws_size;
  const float* pos  = (const float*)d_in[0];
  const float* x    = (const float*)d_in[1];
  const float* Wq_s = (const float*)d_in[2];
  const float* Wq_v = (const float*)d_in[3];
  const float* Wk1  = (const float*)d_in[4];
  const float* Wk2  = (const float*)d_in[5];
  const float* Wv1  = (const float*)d_in[6];
  const float* Wv2  = (const float*)d_in[7];
  const float* Wss  = (const float*)d_in[8];
  const float* Wvv  = (const float*)d_in[9];
  const int* esrc = (const int*)d_in[10];
  const int* edst = (const int*)d_in[11];
  int*   wsi  = (int*)d_ws;
  float* wsf  = (float*)d_ws;
  float* out  = (float*)d_out;

  int2*  sd    = (int2*)(wsi + OFF_SD);
  float* simb  = wsf + OFF_SIMB;
  int*   cnt   = wsi + OFF_CNT;
  int*   start = wsi + OFF_START;
  int*   cur   = wsi + OFF_CUR;

  hipMemsetAsync(cnt, 0, (size_t)N_NODES * sizeof(int), stream);
  hipMemsetAsync(out, 0, (size_t)(N_NODES * 40) * sizeof(float), stream);
  k_hist<<<1000, 256, 0, stream>>>(edst, cnt);
  k_scan<<<1, 1024, 0, stream>>>(cnt, start, cur);
  k_fill<<<1000, 256, 0, stream>>>(esrc, edst, cur, sd);
  k_edge1<<<1000, 256, 0, stream>>>(pos, x, Wq_s, Wq_v, Wk1, Wk2, Wss, Wvv, sd, simb);
  k_norm<<<63, 256, 0, stream>>>(start, simb);
  k_edge2<<<500, 256, 0, stream>>>(pos, x, Wv1, Wv2, sd, simb, out);
}